// Round 5
// baseline (83.111 us; speedup 1.0000x reference)
//
#include <hip/hip_runtime.h>
#include <math.h>

#define N_NODES 100000
#define N_EDGES 1600000
#define IN_DIM  128
#define OUT_DIM 32
#define LEAKY   0.2f

typedef unsigned int uint;
typedef unsigned short ushort;

// pack two floats to bf16 pair (round-to-nearest-even); lo = first channel
__device__ __forceinline__ uint bf16pk(float a, float b) {
    uint ua = __float_as_uint(a); ua = (ua + 0x7fffu + ((ua >> 16) & 1u)) >> 16;
    uint ub = __float_as_uint(b); ub = (ub + 0x7fffu + ((ub >> 16) & 1u)) >> 16;
    return ua | (ub << 16);
}

// ---------------- Kernel A: z = X @ W (bf16-pair out), s_src, s_dst --------
// 1-wave blocks (64 threads) covering 64 rows. Lane = (rg 0..15, q 0..3):
// owns 4 rows' k-quarter q. Each W LDS read (b128) feeds 16 FMAs (4 rows x 4
// ch) -> LDS reads per output /4 vs previous round (which was LDS-pipe-bound
// at ~31us: 256 b128/thread x 6250 waves/CU x 12cy). X windows software-
// prefetched (next window issued before current compute). W sections at
// stride 1160 dwords: bank offset 8q -> the 4 distinct broadcast addresses
// per instruction hit disjoint bank groups.
__global__ __launch_bounds__(64) void gemm_s_kernel(
    const float* __restrict__ X, const float* __restrict__ W,
    const float* __restrict__ a_src, const float* __restrict__ a_dst,
    uint* __restrict__ zu, float* __restrict__ ssrc, float* __restrict__ sdst)
{
    __shared__ float Wl[4 * 1160];     // section q: [kk*36 + c]
    __shared__ float asl[OUT_DIM], adl[OUT_DIM];

    const int t = threadIdx.x;
    for (int i = t; i < IN_DIM * OUT_DIM; i += 64) {
        const int k = i >> 5, c = i & 31;
        Wl[(k >> 5) * 1160 + (k & 31) * 36 + c] = W[i];
    }
    if (t < OUT_DIM) { asl[t] = a_src[t]; adl[t] = a_dst[t]; }
    __syncthreads();

    const int q  = t & 3;
    const int rg = t >> 2;
    const int row0 = blockIdx.x * 64 + (rg << 2);
    const float* wq = &Wl[q * 1160];

    size_t roff[4];
    #pragma unroll
    for (int r = 0; r < 4; ++r) {
        int rr = row0 + r; if (rr > N_NODES - 1) rr = N_NODES - 1;  // clamp loads
        roff[r] = (size_t)rr * IN_DIM + (q << 5);
    }

    float acc[4][32];
    #pragma unroll
    for (int r = 0; r < 4; ++r)
        #pragma unroll
        for (int c = 0; c < 32; ++c) acc[r][c] = 0.f;

    float4 xv[4], xn[4];
    #pragma unroll
    for (int r = 0; r < 4; ++r)
        xv[r] = *reinterpret_cast<const float4*>(&X[roff[r]]);

    #pragma unroll 2
    for (int j = 0; j < 8; ++j) {
        const int jn = (j < 7) ? (j + 1) : 7;          // prefetch next window
        #pragma unroll
        for (int r = 0; r < 4; ++r)
            xn[r] = *reinterpret_cast<const float4*>(&X[roff[r] + (jn << 2)]);
        #pragma unroll
        for (int e = 0; e < 4; ++e) {
            const int kk = (j << 2) + e;
            float xr[4];
            #pragma unroll
            for (int r = 0; r < 4; ++r)
                xr[r] = (e == 0) ? xv[r].x : (e == 1) ? xv[r].y
                      : (e == 2) ? xv[r].z : xv[r].w;
            #pragma unroll
            for (int c4 = 0; c4 < 8; ++c4) {
                const float4 w = *reinterpret_cast<const float4*>(&wq[kk * 36 + (c4 << 2)]);
                #pragma unroll
                for (int r = 0; r < 4; ++r) {
                    acc[r][c4 * 4 + 0] = fmaf(xr[r], w.x, acc[r][c4 * 4 + 0]);
                    acc[r][c4 * 4 + 1] = fmaf(xr[r], w.y, acc[r][c4 * 4 + 1]);
                    acc[r][c4 * 4 + 2] = fmaf(xr[r], w.z, acc[r][c4 * 4 + 2]);
                    acc[r][c4 * 4 + 3] = fmaf(xr[r], w.w, acc[r][c4 * 4 + 3]);
                }
            }
        }
        #pragma unroll
        for (int r = 0; r < 4; ++r) xv[r] = xn[r];
    }

    // quad butterfly: sum the 4 k-quarter partials (all lanes end with full acc)
    #pragma unroll
    for (int r = 0; r < 4; ++r)
        #pragma unroll
        for (int c = 0; c < 32; ++c) {
            acc[r][c] += __shfl_xor(acc[r][c], 1, 64);
            acc[r][c] += __shfl_xor(acc[r][c], 2, 64);
        }

    #pragma unroll
    for (int r = 0; r < 4; ++r) {
        const int row = row0 + r;
        if (row >= N_NODES) continue;
        // attention scalars: full 32-ch dot (static indices; asl/adl b128 broadcast)
        float ss = 0.f, dd = 0.f;
        #pragma unroll
        for (int c4 = 0; c4 < 8; ++c4) {
            const float4 a4 = *reinterpret_cast<const float4*>(&asl[c4 << 2]);
            const float4 d4 = *reinterpret_cast<const float4*>(&adl[c4 << 2]);
            ss = fmaf(acc[r][c4*4+0], a4.x, ss); ss = fmaf(acc[r][c4*4+1], a4.y, ss);
            ss = fmaf(acc[r][c4*4+2], a4.z, ss); ss = fmaf(acc[r][c4*4+3], a4.w, ss);
            dd = fmaf(acc[r][c4*4+0], d4.x, dd); dd = fmaf(acc[r][c4*4+1], d4.y, dd);
            dd = fmaf(acc[r][c4*4+2], d4.z, dd); dd = fmaf(acc[r][c4*4+3], d4.w, dd);
        }
        if (q == 0) ssrc[row] = ss;
        if (q == 1) sdst[row] = dd;

        // lane q stores channels [8q, 8q+8) as uint4 of bf16 pairs
        uint4 pk;
        if (q == 0)
            pk = make_uint4(bf16pk(acc[r][0],  acc[r][1]),  bf16pk(acc[r][2],  acc[r][3]),
                            bf16pk(acc[r][4],  acc[r][5]),  bf16pk(acc[r][6],  acc[r][7]));
        else if (q == 1)
            pk = make_uint4(bf16pk(acc[r][8],  acc[r][9]),  bf16pk(acc[r][10], acc[r][11]),
                            bf16pk(acc[r][12], acc[r][13]), bf16pk(acc[r][14], acc[r][15]));
        else if (q == 2)
            pk = make_uint4(bf16pk(acc[r][16], acc[r][17]), bf16pk(acc[r][18], acc[r][19]),
                            bf16pk(acc[r][20], acc[r][21]), bf16pk(acc[r][22], acc[r][23]));
        else
            pk = make_uint4(bf16pk(acc[r][24], acc[r][25]), bf16pk(acc[r][26], acc[r][27]),
                            bf16pk(acc[r][28], acc[r][29]), bf16pk(acc[r][30], acc[r][31]));
        reinterpret_cast<uint4*>(zu)[row * 4 + q] = pk;
    }
}

// ---------------- Kernel B: CSR offsets from sorted dst ----------------
__global__ __launch_bounds__(256) void offsets_kernel(
    const int* __restrict__ dst, int* __restrict__ off)
{
    const int e = blockIdx.x * blockDim.x + threadIdx.x;
    if (e >= N_EDGES) return;
    const int d = dst[e];
    const int dprev = (e == 0) ? -1 : dst[e - 1];
    for (int n = dprev + 1; n <= d; ++n) off[n] = e;
    if (e == N_EDGES - 1) {
        for (int n = d + 1; n <= N_NODES; ++n) off[n] = N_EDGES;
    }
}

// ---------------- Kernel C1: per-edge softmax weights (coalesced) ----------
__global__ __launch_bounds__(256) void edgew_kernel(
    const float* __restrict__ ssrc, const float* __restrict__ sdst,
    const int* __restrict__ src, const int* __restrict__ dst,
    float* __restrict__ wgt)
{
    const int e = blockIdx.x * 256 + threadIdx.x;
    if (e >= N_EDGES) return;
    float x = ssrc[src[e]] + sdst[dst[e]];
    x = (x > 0.f) ? x : LEAKY * x;
    wgt[e] = __expf(x);
}

// ---------------- Kernel C2: gather + normalize ----------------
// 32-lane group per dst node; lane = (eh = c>>4, ci = c&15). Chunks of 32
// edges: coalesced (w, src*16) staged as float2 in LDS with ZERO-PADDED
// slots so the gather loop is always a multiple of 4 steps (no serial
// remainder). Each step: 1 ds_read_b64 (broadcast) + 1 dword z load covering
// 2 channels; two edges per wave-instruction. 4 gathers in flight per group.
__global__ __launch_bounds__(256) void agg_kernel(
    const uint* __restrict__ zu, const float* __restrict__ wgt,
    const int* __restrict__ src, const int* __restrict__ off,
    float* __restrict__ out)
{
    __shared__ float2 sw[8][40];
    const int t = threadIdx.x;
    const int g = t >> 5, c = t & 31;
    const int n = blockIdx.x * 8 + g;
    if (n >= N_NODES) return;

    const int lo = off[n], hi = off[n + 1];
    const int eh = c >> 4, ci = c & 15;

    float ax = 0.f, ay = 0.f, den = 0.f;

    for (int base = lo; base < hi; base += 32) {
        const int cnt = min(32, hi - base);
        if (c < 8) sw[g][cnt + c] = make_float2(0.f, __int_as_float(0));
        if (c < cnt) {
            const int e = base + c;
            const float wv = wgt[e];
            const int s16 = src[e] << 4;
            den += wv;
            sw[g][c] = make_float2(wv, __int_as_float(s16));
        }
        int nsteps = (cnt + 1) >> 1;
        nsteps = (nsteps + 3) & ~3;            // pad to multiple of 4
        for (int j0 = 0; j0 < nsteps; j0 += 4) {
            const float2 p0 = sw[g][2 * (j0 + 0) + eh];
            const float2 p1 = sw[g][2 * (j0 + 1) + eh];
            const float2 p2 = sw[g][2 * (j0 + 2) + eh];
            const float2 p3 = sw[g][2 * (j0 + 3) + eh];
            const uint u0 = zu[__float_as_int(p0.y) + ci];
            const uint u1 = zu[__float_as_int(p1.y) + ci];
            const uint u2 = zu[__float_as_int(p2.y) + ci];
            const uint u3 = zu[__float_as_int(p3.y) + ci];
            ax = fmaf(p0.x, __uint_as_float(u0 << 16), ax);
            ay = fmaf(p0.x, __uint_as_float(u0 & 0xffff0000u), ay);
            ax = fmaf(p1.x, __uint_as_float(u1 << 16), ax);
            ay = fmaf(p1.x, __uint_as_float(u1 & 0xffff0000u), ay);
            ax = fmaf(p2.x, __uint_as_float(u2 << 16), ax);
            ay = fmaf(p2.x, __uint_as_float(u2 & 0xffff0000u), ay);
            ax = fmaf(p3.x, __uint_as_float(u3 << 16), ax);
            ay = fmaf(p3.x, __uint_as_float(u3 & 0xffff0000u), ay);
        }
    }

    // combine the two edge-halves (same channels, partner lane = c^16)
    ax += __shfl_xor(ax, 16, 64);
    ay += __shfl_xor(ay, 16, 64);
    #pragma unroll
    for (int m = 16; m >= 1; m >>= 1) den += __shfl_xor(den, m, 64);

    if (eh == 0) {
        const float inv = (den > 0.f) ? (1.f / den) : 0.f;
        float2 o;
        o.x = fmaxf(ax * inv, 0.f);
        o.y = fmaxf(ay * inv, 0.f);
        *reinterpret_cast<float2*>(&out[n * OUT_DIM + (ci << 1)]) = o;
    }
}

// ---------------- launch ----------------
extern "C" void kernel_launch(void* const* d_in, const int* in_sizes, int n_in,
                              void* d_out, int out_size, void* d_ws, size_t ws_size,
                              hipStream_t stream) {
    const float* X     = (const float*)d_in[0];
    const float* W     = (const float*)d_in[1];
    const float* a_src = (const float*)d_in[2];
    const float* a_dst = (const float*)d_in[3];
    const int*   src   = (const int*)d_in[4];
    const int*   dst   = (const int*)d_in[5];
    float* out = (float*)d_out;

    char* ws = (char*)d_ws;
    uint*  zu   = (uint*)ws;    ws += (size_t)N_NODES * 16 * sizeof(uint);   // bf16 pairs
    float* ssrc = (float*)ws;   ws += (size_t)N_NODES * sizeof(float);
    float* sdst = (float*)ws;   ws += (size_t)N_NODES * sizeof(float);
    int*   off  = (int*)ws;     ws += (size_t)(N_NODES + 1) * sizeof(int);
    float* wgt  = (float*)ws;   ws += (size_t)N_EDGES * sizeof(float);

    gemm_s_kernel<<<(N_NODES + 63) / 64, 64, 0, stream>>>(X, W, a_src, a_dst, zu, ssrc, sdst);
    offsets_kernel<<<(N_EDGES + 255) / 256, 256, 0, stream>>>(dst, off);
    edgew_kernel<<<(N_EDGES + 255) / 256, 256, 0, stream>>>(ssrc, sdst, src, dst, wgt);
    agg_kernel<<<(N_NODES + 7) / 8, 256, 0, stream>>>(zu, wgt, src, off, out);
}

// Round 6
// 52.091 us; speedup vs baseline: 1.5955x; 1.5955x over previous
//
#include <hip/hip_runtime.h>
#include <math.h>

#define N_NODES 100000
#define N_EDGES 1600000
#define IN_DIM  128
#define OUT_DIM 32
#define LEAKY   0.2f

typedef unsigned int uint;
typedef unsigned short ushort;
typedef __attribute__((ext_vector_type(8))) short bf16x8;
typedef __attribute__((ext_vector_type(4))) float f32x4;

// round-to-nearest-even fp32 -> bf16 (as ushort bit pattern)
__device__ __forceinline__ ushort rne16(float f) {
    uint u = __float_as_uint(f);
    return (ushort)((u + 0x7fffu + ((u >> 16) & 1u)) >> 16);
}

// ---------------- Kernel A: z = X @ W via MFMA, s_src, s_dst ----------------
// Block 256 = 4 waves; wave w owns rows [blk*64 + w*16, +16). Per wave:
// A-frag: lane(l) -> row l&15, k = (l>>4)*8 + j ; loaded as 2 float4 fp32
// directly from global (16 rows x 128B segments = full-line coalescing).
// X split hi/lo bf16 (effective ~17 mantissa bits) so z / scores stay
// accurate; W single RNE-bf16 held entirely in B-frags (32 VGPR) -- this
// removes the W-broadcast LDS stream that bounded rounds 2-5 (8B/FMA).
// C (fp32, col=l&15, row=4*(l>>4)+reg) feeds exact s_src/s_dst butterfly
// and bf16 z stores in agg's layout. No LDS, no barriers.
__global__ __launch_bounds__(256) void gemm_s_kernel(
    const float* __restrict__ X, const float* __restrict__ W,
    const float* __restrict__ a_src, const float* __restrict__ a_dst,
    ushort* __restrict__ zu16, float* __restrict__ ssrc, float* __restrict__ sdst)
{
    const int lane = threadIdx.x & 63;
    const int wv   = threadIdx.x >> 6;
    const int m    = lane & 15;
    const int kg   = lane >> 4;

    const int rowA = blockIdx.x * 64 + wv * 16 + m;       // A-operand row
    const int rA   = (rowA < N_NODES) ? rowA : (N_NODES - 1);
    const float* xp = X + (size_t)rA * IN_DIM + (kg << 3);

    // ---- X loads: all 4 k-steps issued up front (8 independent float4) ----
    float4 xA[4], xB[4];
    #pragma unroll
    for (int s = 0; s < 4; ++s) {
        xA[s] = *reinterpret_cast<const float4*>(xp + (s << 5));
        xB[s] = *reinterpret_cast<const float4*>(xp + (s << 5) + 4);
    }

    // ---- W fragments: cols m and m+16, all 128 k (RNE bf16) ----
    bf16x8 b0[4], b1[4];
    #pragma unroll
    for (int s = 0; s < 4; ++s) {
        #pragma unroll
        for (int j = 0; j < 8; ++j) {
            const int k = (s << 5) + (kg << 3) + j;
            b0[s][j] = (short)rne16(W[k * OUT_DIM + m]);
            b1[s][j] = (short)rne16(W[k * OUT_DIM + m + 16]);
        }
    }

    f32x4 acc0 = {0.f, 0.f, 0.f, 0.f};
    f32x4 acc1 = {0.f, 0.f, 0.f, 0.f};

    #pragma unroll
    for (int s = 0; s < 4; ++s) {
        float xs[8] = {xA[s].x, xA[s].y, xA[s].z, xA[s].w,
                       xB[s].x, xB[s].y, xB[s].z, xB[s].w};
        bf16x8 ah, al;
        #pragma unroll
        for (int j = 0; j < 8; ++j) {
            const uint u = __float_as_uint(xs[j]);
            ah[j] = (short)(u >> 16);                       // truncated hi
            const float lo = xs[j] - __uint_as_float(u & 0xffff0000u);
            al[j] = (short)(__float_as_uint(lo) >> 16);     // residual
        }
        acc0 = __builtin_amdgcn_mfma_f32_16x16x32_bf16(ah, b0[s], acc0, 0, 0, 0);
        acc0 = __builtin_amdgcn_mfma_f32_16x16x32_bf16(al, b0[s], acc0, 0, 0, 0);
        acc1 = __builtin_amdgcn_mfma_f32_16x16x32_bf16(ah, b1[s], acc1, 0, 0, 0);
        acc1 = __builtin_amdgcn_mfma_f32_16x16x32_bf16(al, b1[s], acc1, 0, 0, 0);
    }

    // ---- attention scalars: per-row dot over 32 cols, 16-lane butterfly ----
    const float as0 = a_src[m], as1 = a_src[m + 16];
    const float ad0 = a_dst[m], ad1 = a_dst[m + 16];
    float ps[4], pd[4];
    #pragma unroll
    for (int r = 0; r < 4; ++r) {
        ps[r] = acc0[r] * as0 + acc1[r] * as1;
        pd[r] = acc0[r] * ad0 + acc1[r] * ad1;
    }
    #pragma unroll
    for (int r = 0; r < 4; ++r) {
        #pragma unroll
        for (int msk = 1; msk <= 8; msk <<= 1) {
            ps[r] += __shfl_xor(ps[r], msk, 64);
            pd[r] += __shfl_xor(pd[r], msk, 64);
        }
    }

    const int rbase = blockIdx.x * 64 + wv * 16 + (kg << 2);  // D rows 4kg+r
    if (m == 0) {
        #pragma unroll
        for (int r = 0; r < 4; ++r)
            if (rbase + r < N_NODES) ssrc[rbase + r] = ps[r];
    }
    if (m == 1) {
        #pragma unroll
        for (int r = 0; r < 4; ++r)
            if (rbase + r < N_NODES) sdst[rbase + r] = pd[r];
    }

    // ---- z store: bf16 ushorts, layout zu16[row*32 + c] ----
    #pragma unroll
    for (int r = 0; r < 4; ++r) {
        const int row = rbase + r;
        if (row < N_NODES) {
            zu16[row * OUT_DIM + m]      = rne16(acc0[r]);
            zu16[row * OUT_DIM + m + 16] = rne16(acc1[r]);
        }
    }
}

// ------- Kernel B: CSR offsets from sorted dst + per-edge softmax weight ----
__global__ __launch_bounds__(256) void edge_prep_kernel(
    const int* __restrict__ dst, const int* __restrict__ src,
    const float* __restrict__ ssrc, const float* __restrict__ sdst,
    int* __restrict__ off, float* __restrict__ wgt)
{
    const int e = blockIdx.x * blockDim.x + threadIdx.x;
    if (e >= N_EDGES) return;
    const int d = dst[e];
    const int dprev = (e == 0) ? -1 : dst[e - 1];
    for (int n = dprev + 1; n <= d; ++n) off[n] = e;
    if (e == N_EDGES - 1) {
        for (int n = d + 1; n <= N_NODES; ++n) off[n] = N_EDGES;
    }
    float x = ssrc[src[e]] + sdst[d];
    x = (x > 0.f) ? x : LEAKY * x;
    wgt[e] = __expf(x);
}

// ---------------- Kernel C: gather + normalize ----------------
// 32-lane group per dst node; lane = (eh = c>>4, ci = c&15). Chunks of 32
// edges: coalesced (w, src*16) staged as float2 in LDS with zero-padded
// slots (gather loop always a multiple of 4 steps, no serial remainder).
// Each step: broadcast ds_read_b64 + 1 dword z load covering 2 channels.
__global__ __launch_bounds__(256) void agg_kernel(
    const uint* __restrict__ zu, const float* __restrict__ wgt,
    const int* __restrict__ src, const int* __restrict__ off,
    float* __restrict__ out)
{
    __shared__ float2 sw[8][40];
    const int t = threadIdx.x;
    const int g = t >> 5, c = t & 31;
    const int n = blockIdx.x * 8 + g;
    if (n >= N_NODES) return;

    const int lo = off[n], hi = off[n + 1];
    const int eh = c >> 4, ci = c & 15;

    float ax = 0.f, ay = 0.f, den = 0.f;

    for (int base = lo; base < hi; base += 32) {
        const int cnt = min(32, hi - base);
        if (c < 8) sw[g][cnt + c] = make_float2(0.f, __int_as_float(0));
        if (c < cnt) {
            const int e = base + c;
            const float wv = wgt[e];
            const int s16 = src[e] << 4;
            den += wv;
            sw[g][c] = make_float2(wv, __int_as_float(s16));
        }
        int nsteps = (cnt + 1) >> 1;
        nsteps = (nsteps + 3) & ~3;
        for (int j0 = 0; j0 < nsteps; j0 += 4) {
            const float2 p0 = sw[g][2 * (j0 + 0) + eh];
            const float2 p1 = sw[g][2 * (j0 + 1) + eh];
            const float2 p2 = sw[g][2 * (j0 + 2) + eh];
            const float2 p3 = sw[g][2 * (j0 + 3) + eh];
            const uint u0 = zu[__float_as_int(p0.y) + ci];
            const uint u1 = zu[__float_as_int(p1.y) + ci];
            const uint u2 = zu[__float_as_int(p2.y) + ci];
            const uint u3 = zu[__float_as_int(p3.y) + ci];
            ax = fmaf(p0.x, __uint_as_float(u0 << 16), ax);
            ay = fmaf(p0.x, __uint_as_float(u0 & 0xffff0000u), ay);
            ax = fmaf(p1.x, __uint_as_float(u1 << 16), ax);
            ay = fmaf(p1.x, __uint_as_float(u1 & 0xffff0000u), ay);
            ax = fmaf(p2.x, __uint_as_float(u2 << 16), ax);
            ay = fmaf(p2.x, __uint_as_float(u2 & 0xffff0000u), ay);
            ax = fmaf(p3.x, __uint_as_float(u3 << 16), ax);
            ay = fmaf(p3.x, __uint_as_float(u3 & 0xffff0000u), ay);
        }
    }

    ax += __shfl_xor(ax, 16, 64);
    ay += __shfl_xor(ay, 16, 64);
    #pragma unroll
    for (int msk = 16; msk >= 1; msk >>= 1) den += __shfl_xor(den, msk, 64);

    if (eh == 0) {
        const float inv = (den > 0.f) ? (1.f / den) : 0.f;
        float2 o;
        o.x = fmaxf(ax * inv, 0.f);
        o.y = fmaxf(ay * inv, 0.f);
        *reinterpret_cast<float2*>(&out[n * OUT_DIM + (ci << 1)]) = o;
    }
}

// ---------------- launch ----------------
extern "C" void kernel_launch(void* const* d_in, const int* in_sizes, int n_in,
                              void* d_out, int out_size, void* d_ws, size_t ws_size,
                              hipStream_t stream) {
    const float* X     = (const float*)d_in[0];
    const float* W     = (const float*)d_in[1];
    const float* a_src = (const float*)d_in[2];
    const float* a_dst = (const float*)d_in[3];
    const int*   src   = (const int*)d_in[4];
    const int*   dst   = (const int*)d_in[5];
    float* out = (float*)d_out;

    char* ws = (char*)d_ws;
    ushort* zu16 = (ushort*)ws; ws += (size_t)N_NODES * OUT_DIM * sizeof(ushort);
    float* ssrc  = (float*)ws;  ws += (size_t)N_NODES * sizeof(float);
    float* sdst  = (float*)ws;  ws += (size_t)N_NODES * sizeof(float);
    int*   off   = (int*)ws;    ws += (size_t)(N_NODES + 1) * sizeof(int);
    float* wgt   = (float*)ws;  ws += (size_t)N_EDGES * sizeof(float);

    gemm_s_kernel<<<(N_NODES + 63) / 64, 256, 0, stream>>>(X, W, a_src, a_dst, zu16, ssrc, sdst);
    edge_prep_kernel<<<(N_EDGES + 255) / 256, 256, 0, stream>>>(dst, src, ssrc, sdst, off, wgt);
    agg_kernel<<<(N_NODES + 7) / 8, 256, 0, stream>>>((const uint*)zu16, wgt, src, off, out);
}

// Round 7
// 49.392 us; speedup vs baseline: 1.6827x; 1.0546x over previous
//
#include <hip/hip_runtime.h>
#include <math.h>

#define N_NODES 100000
#define N_EDGES 1600000
#define IN_DIM  128
#define OUT_DIM 32
#define LEAKY   0.2f

typedef unsigned int uint;
typedef unsigned short ushort;
typedef __attribute__((ext_vector_type(8))) short bf16x8;
typedef __attribute__((ext_vector_type(4))) float f32x4;

// round-to-nearest-even fp32 -> bf16 (as ushort bit pattern)
__device__ __forceinline__ ushort rne16(float f) {
    uint u = __float_as_uint(f);
    return (ushort)((u + 0x7fffu + ((u >> 16) & 1u)) >> 16);
}

// ---------------- Kernel A: z = X @ W via MFMA, s_src, s_dst ----------------
// (unchanged from round 6 — near its HBM floor)
__global__ __launch_bounds__(256) void gemm_s_kernel(
    const float* __restrict__ X, const float* __restrict__ W,
    const float* __restrict__ a_src, const float* __restrict__ a_dst,
    ushort* __restrict__ zu16, float* __restrict__ ssrc, float* __restrict__ sdst)
{
    const int lane = threadIdx.x & 63;
    const int wv   = threadIdx.x >> 6;
    const int m    = lane & 15;
    const int kg   = lane >> 4;

    const int rowA = blockIdx.x * 64 + wv * 16 + m;
    const int rA   = (rowA < N_NODES) ? rowA : (N_NODES - 1);
    const float* xp = X + (size_t)rA * IN_DIM + (kg << 3);

    float4 xA[4], xB[4];
    #pragma unroll
    for (int s = 0; s < 4; ++s) {
        xA[s] = *reinterpret_cast<const float4*>(xp + (s << 5));
        xB[s] = *reinterpret_cast<const float4*>(xp + (s << 5) + 4);
    }

    bf16x8 b0[4], b1[4];
    #pragma unroll
    for (int s = 0; s < 4; ++s) {
        #pragma unroll
        for (int j = 0; j < 8; ++j) {
            const int k = (s << 5) + (kg << 3) + j;
            b0[s][j] = (short)rne16(W[k * OUT_DIM + m]);
            b1[s][j] = (short)rne16(W[k * OUT_DIM + m + 16]);
        }
    }

    f32x4 acc0 = {0.f, 0.f, 0.f, 0.f};
    f32x4 acc1 = {0.f, 0.f, 0.f, 0.f};

    #pragma unroll
    for (int s = 0; s < 4; ++s) {
        float xs[8] = {xA[s].x, xA[s].y, xA[s].z, xA[s].w,
                       xB[s].x, xB[s].y, xB[s].z, xB[s].w};
        bf16x8 ah, al;
        #pragma unroll
        for (int j = 0; j < 8; ++j) {
            const uint u = __float_as_uint(xs[j]);
            ah[j] = (short)(u >> 16);
            const float lo = xs[j] - __uint_as_float(u & 0xffff0000u);
            al[j] = (short)(__float_as_uint(lo) >> 16);
        }
        acc0 = __builtin_amdgcn_mfma_f32_16x16x32_bf16(ah, b0[s], acc0, 0, 0, 0);
        acc0 = __builtin_amdgcn_mfma_f32_16x16x32_bf16(al, b0[s], acc0, 0, 0, 0);
        acc1 = __builtin_amdgcn_mfma_f32_16x16x32_bf16(ah, b1[s], acc1, 0, 0, 0);
        acc1 = __builtin_amdgcn_mfma_f32_16x16x32_bf16(al, b1[s], acc1, 0, 0, 0);
    }

    const float as0 = a_src[m], as1 = a_src[m + 16];
    const float ad0 = a_dst[m], ad1 = a_dst[m + 16];
    float ps[4], pd[4];
    #pragma unroll
    for (int r = 0; r < 4; ++r) {
        ps[r] = acc0[r] * as0 + acc1[r] * as1;
        pd[r] = acc0[r] * ad0 + acc1[r] * ad1;
    }
    #pragma unroll
    for (int r = 0; r < 4; ++r) {
        #pragma unroll
        for (int msk = 1; msk <= 8; msk <<= 1) {
            ps[r] += __shfl_xor(ps[r], msk, 64);
            pd[r] += __shfl_xor(pd[r], msk, 64);
        }
    }

    const int rbase = blockIdx.x * 64 + wv * 16 + (kg << 2);
    if (m == 0) {
        #pragma unroll
        for (int r = 0; r < 4; ++r)
            if (rbase + r < N_NODES) ssrc[rbase + r] = ps[r];
    }
    if (m == 1) {
        #pragma unroll
        for (int r = 0; r < 4; ++r)
            if (rbase + r < N_NODES) sdst[rbase + r] = pd[r];
    }

    #pragma unroll
    for (int r = 0; r < 4; ++r) {
        const int row = rbase + r;
        if (row < N_NODES) {
            zu16[row * OUT_DIM + m]      = rne16(acc0[r]);
            zu16[row * OUT_DIM + m + 16] = rne16(acc1[r]);
        }
    }
}

// ---------------- Kernel B: CSR offsets from sorted dst ----------------
__global__ __launch_bounds__(256) void offsets_kernel(
    const int* __restrict__ dst, int* __restrict__ off)
{
    const int e = blockIdx.x * blockDim.x + threadIdx.x;
    if (e >= N_EDGES) return;
    const int d = dst[e];
    const int dprev = (e == 0) ? -1 : dst[e - 1];
    for (int n = dprev + 1; n <= d; ++n) off[n] = e;
    if (e == N_EDGES - 1) {
        for (int n = d + 1; n <= N_NODES; ++n) off[n] = N_EDGES;
    }
}

// ---------------- Kernel C: fused exp + gather + normalize ----------------
// 32-lane group per dst node. Staging (per 32-edge chunk): coalesced src
// load, L2-hot ssrc gather, exp -> (w, s*16) in LDS, 32 zero-pad slots.
// Gather: lane = (eh=c>>2 edge slot, ci=c&3); ONE unrolled 4-step block
// covers the whole chunk: 4 ds_read_b64 (quad broadcast) + 4 b128 z loads
// (8 bf16 channels each) all in flight, then 32 unpack-FMAs. acc: 8
// channels/lane; butterfly over eh at the end; eh==0 lanes store 2 float4.
__global__ __launch_bounds__(256) void agg_kernel(
    const uint* __restrict__ zu, const float* __restrict__ ssrc,
    const float* __restrict__ sdst, const int* __restrict__ src,
    const int* __restrict__ off, float* __restrict__ out)
{
    __shared__ float2 sw[8][64];
    const int t = threadIdx.x;
    const int g = t >> 5, c = t & 31;
    const int n = blockIdx.x * 8 + g;
    if (n >= N_NODES) return;

    const int lo = off[n], hi = off[n + 1];
    const float sd = sdst[n];
    const int eh = c >> 2;     // edge slot 0..7
    const int ci = c & 3;      // uint4 index within z row (8 channels)

    float a0 = 0.f, a1 = 0.f, a2 = 0.f, a3 = 0.f;
    float a4 = 0.f, a5 = 0.f, a6 = 0.f, a7 = 0.f;
    float den = 0.f;

    for (int base = lo; base < hi; base += 32) {
        const int cnt = min(32, hi - base);
        sw[g][cnt + c] = make_float2(0.f, __int_as_float(0));   // zero-pad 32 slots
        if (c < cnt) {
            const int e = base + c;
            const int s = src[e];
            float x = ssrc[s] + sd;
            x = (x > 0.f) ? x : LEAKY * x;
            const float v = __expf(x);
            den += v;
            sw[g][c] = make_float2(v, __int_as_float(s << 4));
        }
        const float2 p0 = sw[g][eh];
        const float2 p1 = sw[g][8 + eh];
        const float2 p2 = sw[g][16 + eh];
        const float2 p3 = sw[g][24 + eh];
        const uint4 u0 = *reinterpret_cast<const uint4*>(zu + __float_as_int(p0.y) + (ci << 2));
        const uint4 u1 = *reinterpret_cast<const uint4*>(zu + __float_as_int(p1.y) + (ci << 2));
        const uint4 u2 = *reinterpret_cast<const uint4*>(zu + __float_as_int(p2.y) + (ci << 2));
        const uint4 u3 = *reinterpret_cast<const uint4*>(zu + __float_as_int(p3.y) + (ci << 2));
        #define ACC8(P, U)                                                  \
            a0 = fmaf(P.x, __uint_as_float(U.x << 16),         a0);         \
            a1 = fmaf(P.x, __uint_as_float(U.x & 0xffff0000u), a1);         \
            a2 = fmaf(P.x, __uint_as_float(U.y << 16),         a2);         \
            a3 = fmaf(P.x, __uint_as_float(U.y & 0xffff0000u), a3);         \
            a4 = fmaf(P.x, __uint_as_float(U.z << 16),         a4);         \
            a5 = fmaf(P.x, __uint_as_float(U.z & 0xffff0000u), a5);         \
            a6 = fmaf(P.x, __uint_as_float(U.w << 16),         a6);         \
            a7 = fmaf(P.x, __uint_as_float(U.w & 0xffff0000u), a7);
        ACC8(p0, u0) ACC8(p1, u1) ACC8(p2, u2) ACC8(p3, u3)
        #undef ACC8
    }

    // reduce over the 8 edge slots (lanes sharing ci) + den over 32 lanes
    #pragma unroll
    for (int msk = 4; msk <= 16; msk <<= 1) {
        a0 += __shfl_xor(a0, msk, 64); a1 += __shfl_xor(a1, msk, 64);
        a2 += __shfl_xor(a2, msk, 64); a3 += __shfl_xor(a3, msk, 64);
        a4 += __shfl_xor(a4, msk, 64); a5 += __shfl_xor(a5, msk, 64);
        a6 += __shfl_xor(a6, msk, 64); a7 += __shfl_xor(a7, msk, 64);
    }
    #pragma unroll
    for (int msk = 16; msk >= 1; msk >>= 1) den += __shfl_xor(den, msk, 64);

    if (eh == 0) {
        const float inv = (den > 0.f) ? (1.f / den) : 0.f;
        float4 o0, o1;
        o0.x = fmaxf(a0 * inv, 0.f); o0.y = fmaxf(a1 * inv, 0.f);
        o0.z = fmaxf(a2 * inv, 0.f); o0.w = fmaxf(a3 * inv, 0.f);
        o1.x = fmaxf(a4 * inv, 0.f); o1.y = fmaxf(a5 * inv, 0.f);
        o1.z = fmaxf(a6 * inv, 0.f); o1.w = fmaxf(a7 * inv, 0.f);
        float* op = &out[n * OUT_DIM + (ci << 3)];
        *reinterpret_cast<float4*>(op)     = o0;
        *reinterpret_cast<float4*>(op + 4) = o1;
    }
}

// ---------------- launch ----------------
extern "C" void kernel_launch(void* const* d_in, const int* in_sizes, int n_in,
                              void* d_out, int out_size, void* d_ws, size_t ws_size,
                              hipStream_t stream) {
    const float* X     = (const float*)d_in[0];
    const float* W     = (const float*)d_in[1];
    const float* a_src = (const float*)d_in[2];
    const float* a_dst = (const float*)d_in[3];
    const int*   src   = (const int*)d_in[4];
    const int*   dst   = (const int*)d_in[5];
    float* out = (float*)d_out;

    char* ws = (char*)d_ws;
    ushort* zu16 = (ushort*)ws; ws += (size_t)N_NODES * OUT_DIM * sizeof(ushort);
    float* ssrc  = (float*)ws;  ws += (size_t)N_NODES * sizeof(float);
    float* sdst  = (float*)ws;  ws += (size_t)N_NODES * sizeof(float);
    int*   off   = (int*)ws;    ws += (size_t)(N_NODES + 1) * sizeof(int);

    offsets_kernel<<<(N_EDGES + 255) / 256, 256, 0, stream>>>(dst, off);
    gemm_s_kernel<<<(N_NODES + 63) / 64, 256, 0, stream>>>(X, W, a_src, a_dst, zu16, ssrc, sdst);
    agg_kernel<<<(N_NODES + 7) / 8, 256, 0, stream>>>((const uint*)zu16, ssrc, sdst, src, off, out);
}

// Round 8
// 43.114 us; speedup vs baseline: 1.9277x; 1.1456x over previous
//
#include <hip/hip_runtime.h>
#include <math.h>

#define N_NODES 100000
#define N_EDGES 1600000
#define IN_DIM  128
#define OUT_DIM 32
#define LEAKY   0.2f

#define GEMM_NBLK 1563        // ceil(N_NODES/64)
#define OFF_NBLK  6250        // ceil(N_EDGES/256)

typedef unsigned int uint;
typedef unsigned short ushort;
typedef __attribute__((ext_vector_type(8))) short bf16x8;
typedef __attribute__((ext_vector_type(4))) float f32x4;

// round-to-nearest-even fp32 -> bf16 (as ushort bit pattern)
__device__ __forceinline__ ushort rne16(float f) {
    uint u = __float_as_uint(f);
    return (ushort)((u + 0x7fffu + ((u >> 16) & 1u)) >> 16);
}

// ------- Kernel A+B fused: MFMA gemm (blocks < GEMM_NBLK) | CSR offsets -----
// gemm part: W^T staged ONCE per block as bf16 in LDS (WT[c][k], row stride
// 136 ushorts -> 16B-aligned rows, near-floor b128 reads). B-fragment = one
// ds_read_b128 (replaces 64 scalar global W loads + 192 VALU of per-wave RNE
// conversion that made round-6 gemm 2.5x its HBM floor). X loads issued
// before staging so HBM latency hides under it. Fragment values bit-identical
// to round 6. offsets part: blocks >= GEMM_NBLK, same body as before; its
// 12.8MB stream overlaps the gemm instead of serializing as its own launch.
__global__ __launch_bounds__(256) void gemm_off_kernel(
    const float* __restrict__ X, const float* __restrict__ W,
    const float* __restrict__ a_src, const float* __restrict__ a_dst,
    const int* __restrict__ dst,
    ushort* __restrict__ zu16, float* __restrict__ ssrc, float* __restrict__ sdst,
    int* __restrict__ off)
{
    __shared__ ushort WT[32][136];     // WT[c][k], bf16 bits; 272B rows
    __shared__ float asl[OUT_DIM], adl[OUT_DIM];

    if (blockIdx.x >= GEMM_NBLK) {
        // ---------------- offsets body ----------------
        const int e = (blockIdx.x - GEMM_NBLK) * 256 + threadIdx.x;
        if (e >= N_EDGES) return;
        const int d = dst[e];
        const int dprev = (e == 0) ? -1 : dst[e - 1];
        for (int n = dprev + 1; n <= d; ++n) off[n] = e;
        if (e == N_EDGES - 1) {
            for (int n = d + 1; n <= N_NODES; ++n) off[n] = N_EDGES;
        }
        return;
    }

    // ---------------- gemm body ----------------
    const int t    = threadIdx.x;
    const int lane = t & 63;
    const int wv   = t >> 6;
    const int m    = lane & 15;
    const int kg   = lane >> 4;

    // X loads first: 8 independent float4 per lane, in flight during staging
    const int rowA = blockIdx.x * 64 + wv * 16 + m;
    const int rA   = (rowA < N_NODES) ? rowA : (N_NODES - 1);
    const float* xp = X + (size_t)rA * IN_DIM + (kg << 3);
    float4 xA[4], xB[4];
    #pragma unroll
    for (int s = 0; s < 4; ++s) {
        xA[s] = *reinterpret_cast<const float4*>(xp + (s << 5));
        xB[s] = *reinterpret_cast<const float4*>(xp + (s << 5) + 4);
    }

    // W^T staging: thread t covers col c = t&31, k-chunk kh = t>>5 (16 k's)
    {
        const int c = t & 31, kh = t >> 5;
        uint pk[8];
        #pragma unroll
        for (int j2 = 0; j2 < 8; ++j2) {
            const float w0 = W[(kh * 16 + 2 * j2)     * OUT_DIM + c];
            const float w1 = W[(kh * 16 + 2 * j2 + 1) * OUT_DIM + c];
            pk[j2] = (uint)rne16(w0) | ((uint)rne16(w1) << 16);
        }
        uint4* wd = reinterpret_cast<uint4*>(&WT[c][kh * 16]);
        wd[0] = make_uint4(pk[0], pk[1], pk[2], pk[3]);
        wd[1] = make_uint4(pk[4], pk[5], pk[6], pk[7]);
        if (t < OUT_DIM) { asl[t] = a_src[t]; adl[t] = a_dst[t]; }
    }
    __syncthreads();

    // B fragments: one ds_read_b128 each (cols m and m+16, k-window of s,kg)
    bf16x8 b0[4], b1[4];
    #pragma unroll
    for (int s = 0; s < 4; ++s) {
        b0[s] = *reinterpret_cast<bf16x8*>(&WT[m][(s << 5) + (kg << 3)]);
        b1[s] = *reinterpret_cast<bf16x8*>(&WT[m + 16][(s << 5) + (kg << 3)]);
    }

    f32x4 acc0 = {0.f, 0.f, 0.f, 0.f};
    f32x4 acc1 = {0.f, 0.f, 0.f, 0.f};

    #pragma unroll
    for (int s = 0; s < 4; ++s) {
        float xs[8] = {xA[s].x, xA[s].y, xA[s].z, xA[s].w,
                       xB[s].x, xB[s].y, xB[s].z, xB[s].w};
        bf16x8 ah, al;
        #pragma unroll
        for (int j = 0; j < 8; ++j) {
            const uint u = __float_as_uint(xs[j]);
            ah[j] = (short)(u >> 16);                     // truncated hi
            const float lo = xs[j] - __uint_as_float(u & 0xffff0000u);
            al[j] = (short)(__float_as_uint(lo) >> 16);   // residual
        }
        acc0 = __builtin_amdgcn_mfma_f32_16x16x32_bf16(ah, b0[s], acc0, 0, 0, 0);
        acc0 = __builtin_amdgcn_mfma_f32_16x16x32_bf16(al, b0[s], acc0, 0, 0, 0);
        acc1 = __builtin_amdgcn_mfma_f32_16x16x32_bf16(ah, b1[s], acc1, 0, 0, 0);
        acc1 = __builtin_amdgcn_mfma_f32_16x16x32_bf16(al, b1[s], acc1, 0, 0, 0);
    }

    // attention scalars: per-row dot over 32 cols, 16-lane butterfly
    const float as0 = asl[m], as1 = asl[m + 16];
    const float ad0 = adl[m], ad1 = adl[m + 16];
    float ps[4], pd[4];
    #pragma unroll
    for (int r = 0; r < 4; ++r) {
        ps[r] = acc0[r] * as0 + acc1[r] * as1;
        pd[r] = acc0[r] * ad0 + acc1[r] * ad1;
    }
    #pragma unroll
    for (int r = 0; r < 4; ++r) {
        #pragma unroll
        for (int msk = 1; msk <= 8; msk <<= 1) {
            ps[r] += __shfl_xor(ps[r], msk, 64);
            pd[r] += __shfl_xor(pd[r], msk, 64);
        }
    }

    const int rbase = blockIdx.x * 64 + wv * 16 + (kg << 2);  // D rows 4kg+r
    if (m == 0) {
        #pragma unroll
        for (int r = 0; r < 4; ++r)
            if (rbase + r < N_NODES) ssrc[rbase + r] = ps[r];
    }
    if (m == 1) {
        #pragma unroll
        for (int r = 0; r < 4; ++r)
            if (rbase + r < N_NODES) sdst[rbase + r] = pd[r];
    }

    // z store: bf16 ushorts, layout zu16[row*32 + c]
    #pragma unroll
    for (int r = 0; r < 4; ++r) {
        const int row = rbase + r;
        if (row < N_NODES) {
            zu16[row * OUT_DIM + m]      = rne16(acc0[r]);
            zu16[row * OUT_DIM + m + 16] = rne16(acc1[r]);
        }
    }
}

// ---------------- Kernel C: fused exp + gather + normalize ----------------
// (unchanged from round 7)
__global__ __launch_bounds__(256) void agg_kernel(
    const uint* __restrict__ zu, const float* __restrict__ ssrc,
    const float* __restrict__ sdst, const int* __restrict__ src,
    const int* __restrict__ off, float* __restrict__ out)
{
    __shared__ float2 sw[8][64];
    const int t = threadIdx.x;
    const int g = t >> 5, c = t & 31;
    const int n = blockIdx.x * 8 + g;
    if (n >= N_NODES) return;

    const int lo = off[n], hi = off[n + 1];
    const float sd = sdst[n];
    const int eh = c >> 2;     // edge slot 0..7
    const int ci = c & 3;      // uint4 index within z row

    float a0 = 0.f, a1 = 0.f, a2 = 0.f, a3 = 0.f;
    float a4 = 0.f, a5 = 0.f, a6 = 0.f, a7 = 0.f;
    float den = 0.f;

    for (int base = lo; base < hi; base += 32) {
        const int cnt = min(32, hi - base);
        sw[g][cnt + c] = make_float2(0.f, __int_as_float(0));
        if (c < cnt) {
            const int e = base + c;
            const int s = src[e];
            float x = ssrc[s] + sd;
            x = (x > 0.f) ? x : LEAKY * x;
            const float v = __expf(x);
            den += v;
            sw[g][c] = make_float2(v, __int_as_float(s << 4));
        }
        const float2 p0 = sw[g][eh];
        const float2 p1 = sw[g][8 + eh];
        const float2 p2 = sw[g][16 + eh];
        const float2 p3 = sw[g][24 + eh];
        const uint4 u0 = *reinterpret_cast<const uint4*>(zu + __float_as_int(p0.y) + (ci << 2));
        const uint4 u1 = *reinterpret_cast<const uint4*>(zu + __float_as_int(p1.y) + (ci << 2));
        const uint4 u2 = *reinterpret_cast<const uint4*>(zu + __float_as_int(p2.y) + (ci << 2));
        const uint4 u3 = *reinterpret_cast<const uint4*>(zu + __float_as_int(p3.y) + (ci << 2));
        #define ACC8(P, U)                                                  \
            a0 = fmaf(P.x, __uint_as_float(U.x << 16),         a0);         \
            a1 = fmaf(P.x, __uint_as_float(U.x & 0xffff0000u), a1);         \
            a2 = fmaf(P.x, __uint_as_float(U.y << 16),         a2);         \
            a3 = fmaf(P.x, __uint_as_float(U.y & 0xffff0000u), a3);         \
            a4 = fmaf(P.x, __uint_as_float(U.z << 16),         a4);         \
            a5 = fmaf(P.x, __uint_as_float(U.z & 0xffff0000u), a5);         \
            a6 = fmaf(P.x, __uint_as_float(U.w << 16),         a6);         \
            a7 = fmaf(P.x, __uint_as_float(U.w & 0xffff0000u), a7);
        ACC8(p0, u0) ACC8(p1, u1) ACC8(p2, u2) ACC8(p3, u3)
        #undef ACC8
    }

    #pragma unroll
    for (int msk = 4; msk <= 16; msk <<= 1) {
        a0 += __shfl_xor(a0, msk, 64); a1 += __shfl_xor(a1, msk, 64);
        a2 += __shfl_xor(a2, msk, 64); a3 += __shfl_xor(a3, msk, 64);
        a4 += __shfl_xor(a4, msk, 64); a5 += __shfl_xor(a5, msk, 64);
        a6 += __shfl_xor(a6, msk, 64); a7 += __shfl_xor(a7, msk, 64);
    }
    #pragma unroll
    for (int msk = 16; msk >= 1; msk >>= 1) den += __shfl_xor(den, msk, 64);

    if (eh == 0) {
        const float inv = (den > 0.f) ? (1.f / den) : 0.f;
        float4 o0, o1;
        o0.x = fmaxf(a0 * inv, 0.f); o0.y = fmaxf(a1 * inv, 0.f);
        o0.z = fmaxf(a2 * inv, 0.f); o0.w = fmaxf(a3 * inv, 0.f);
        o1.x = fmaxf(a4 * inv, 0.f); o1.y = fmaxf(a5 * inv, 0.f);
        o1.z = fmaxf(a6 * inv, 0.f); o1.w = fmaxf(a7 * inv, 0.f);
        float* op = &out[n * OUT_DIM + (ci << 3)];
        *reinterpret_cast<float4*>(op)     = o0;
        *reinterpret_cast<float4*>(op + 4) = o1;
    }
}

// ---------------- launch ----------------
extern "C" void kernel_launch(void* const* d_in, const int* in_sizes, int n_in,
                              void* d_out, int out_size, void* d_ws, size_t ws_size,
                              hipStream_t stream) {
    const float* X     = (const float*)d_in[0];
    const float* W     = (const float*)d_in[1];
    const float* a_src = (const float*)d_in[2];
    const float* a_dst = (const float*)d_in[3];
    const int*   src   = (const int*)d_in[4];
    const int*   dst   = (const int*)d_in[5];
    float* out = (float*)d_out;

    char* ws = (char*)d_ws;
    ushort* zu16 = (ushort*)ws; ws += (size_t)N_NODES * OUT_DIM * sizeof(ushort);
    float* ssrc  = (float*)ws;  ws += (size_t)N_NODES * sizeof(float);
    float* sdst  = (float*)ws;  ws += (size_t)N_NODES * sizeof(float);
    int*   off   = (int*)ws;    ws += (size_t)(N_NODES + 1) * sizeof(int);

    gemm_off_kernel<<<GEMM_NBLK + OFF_NBLK, 256, 0, stream>>>(
        X, W, a_src, a_dst, dst, zu16, ssrc, sdst, off);
    agg_kernel<<<(N_NODES + 7) / 8, 256, 0, stream>>>((const uint*)zu16, ssrc, sdst, src, off, out);
}